// Round 1
// baseline (6135.508 us; speedup 1.0000x reference)
//
#include <hip/hip_runtime.h>
#include <math.h>

#define NDIM 128   // in_dim = hid = out_dim
#define H2   256   // 2*hid

// ---------------- degree + norm ----------------
__global__ void deg_kernel(const int* __restrict__ src, const int* __restrict__ dst,
                           float* __restrict__ deg_out, float* __restrict__ deg_in, int E) {
    int e = blockIdx.x * blockDim.x + threadIdx.x;
    if (e < E) {
        atomicAdd(&deg_out[src[e]], 1.0f);
        atomicAdd(&deg_in[dst[e]], 1.0f);
    }
}

__global__ void rsqrt_kernel(float* __restrict__ d, int n) {
    int i = blockIdx.x * blockDim.x + threadIdx.x;
    if (i < n) {
        float v = d[i];
        d[i] = rsqrtf(v > 1.0f ? v : 1.0f);
    }
}

// ---------------- scatter-aggregate: agg[dst] += X[src] * rs[src] ----------------
// 32 lanes per edge, float4 per lane (128 floats per row).
__global__ void scatter_kernel(const float* __restrict__ X, const int* __restrict__ src,
                               const int* __restrict__ dst, const float* __restrict__ rs,
                               float* __restrict__ agg, int E) {
    int tid = blockIdx.x * blockDim.x + threadIdx.x;
    int e    = tid >> 5;
    int lane = tid & 31;
    if (e >= E) return;
    int s = src[e], d = dst[e];
    float sc = rs[s];
    const float4* xr = (const float4*)(X + (size_t)s * NDIM);
    float4 v = xr[lane];
    float* ar = agg + (size_t)d * NDIM + lane * 4;
    atomicAdd(ar + 0, v.x * sc);
    atomicAdd(ar + 1, v.y * sc);
    atomicAdd(ar + 2, v.z * sc);
    atomicAdd(ar + 3, v.w * sc);
}

// ---------------- fused GEMM ----------------
// C[M x Nc] = actOut( (actIn(A*rsIn[r]+bIn[k]) @ W) * rsOut[r] + bOut[c] )
// 64x64 tile, 256 threads (16x16), 4x4 per thread, BK=16.
__global__ __launch_bounds__(256) void gemm_kernel(
    const float* __restrict__ A, const float* __restrict__ W, float* __restrict__ C,
    int M, int K, int Nc,
    const float* __restrict__ rsIn, const float* __restrict__ bIn, int actIn,
    const float* __restrict__ rsOut, const float* __restrict__ bOut, int actOut)
{
    __shared__ float As[16][65];
    __shared__ float Bs[16][65];
    int tid = threadIdx.x;
    int tx = tid & 15, ty = tid >> 4;
    int rowBase = blockIdx.x * 64;
    int colBase = blockIdx.y * 64;

    // A-tile load mapping: thread -> (row 0..63, 4 consecutive k)
    int arow = tid >> 2;
    int akq  = (tid & 3) * 4;
    int grow = rowBase + arow;
    float rsv = 1.0f;
    if (rsIn && grow < M) rsv = rsIn[grow];
    // B-tile load mapping: thread -> (k 0..15, 4 consecutive cols)
    int bk = tid >> 4;
    int bc = (tid & 15) * 4;

    float acc[4][4] = {};

    for (int k0 = 0; k0 < K; k0 += 16) {
        float4 av = make_float4(0.f, 0.f, 0.f, 0.f);
        if (grow < M) av = *(const float4*)(A + (size_t)grow * K + k0 + akq);
        if (rsIn) { av.x *= rsv; av.y *= rsv; av.z *= rsv; av.w *= rsv; }
        if (bIn) {
            av.x += bIn[k0 + akq + 0];
            av.y += bIn[k0 + akq + 1];
            av.z += bIn[k0 + akq + 2];
            av.w += bIn[k0 + akq + 3];
        }
        if (actIn == 1) {
            av.x = fmaxf(av.x, 0.f); av.y = fmaxf(av.y, 0.f);
            av.z = fmaxf(av.z, 0.f); av.w = fmaxf(av.w, 0.f);
        }
        As[akq + 0][arow] = av.x;
        As[akq + 1][arow] = av.y;
        As[akq + 2][arow] = av.z;
        As[akq + 3][arow] = av.w;

        float4 bv = *(const float4*)(W + (size_t)(k0 + bk) * Nc + colBase + bc);
        Bs[bk][bc + 0] = bv.x;
        Bs[bk][bc + 1] = bv.y;
        Bs[bk][bc + 2] = bv.z;
        Bs[bk][bc + 3] = bv.w;

        __syncthreads();
#pragma unroll
        for (int kk = 0; kk < 16; ++kk) {
            float a0 = As[kk][ty * 4 + 0];
            float a1 = As[kk][ty * 4 + 1];
            float a2 = As[kk][ty * 4 + 2];
            float a3 = As[kk][ty * 4 + 3];
            float b0 = Bs[kk][tx * 4 + 0];
            float b1 = Bs[kk][tx * 4 + 1];
            float b2 = Bs[kk][tx * 4 + 2];
            float b3 = Bs[kk][tx * 4 + 3];
            acc[0][0] += a0 * b0; acc[0][1] += a0 * b1; acc[0][2] += a0 * b2; acc[0][3] += a0 * b3;
            acc[1][0] += a1 * b0; acc[1][1] += a1 * b1; acc[1][2] += a1 * b2; acc[1][3] += a1 * b3;
            acc[2][0] += a2 * b0; acc[2][1] += a2 * b1; acc[2][2] += a2 * b2; acc[2][3] += a2 * b3;
            acc[3][0] += a3 * b0; acc[3][1] += a3 * b1; acc[3][2] += a3 * b2; acc[3][3] += a3 * b3;
        }
        __syncthreads();
    }

    int r0 = rowBase + ty * 4;
    int c0 = colBase + tx * 4;
#pragma unroll
    for (int i = 0; i < 4; ++i) {
        int r = r0 + i;
        if (r >= M) continue;
        float rs = rsOut ? rsOut[r] : 1.0f;
        float4 v;
        v.x = acc[i][0] * rs; v.y = acc[i][1] * rs; v.z = acc[i][2] * rs; v.w = acc[i][3] * rs;
        if (bOut) {
            v.x += bOut[c0 + 0]; v.y += bOut[c0 + 1]; v.z += bOut[c0 + 2]; v.w += bOut[c0 + 3];
        }
        if (actOut == 1) {
            v.x = fmaxf(v.x, 0.f); v.y = fmaxf(v.y, 0.f);
            v.z = fmaxf(v.z, 0.f); v.w = fmaxf(v.w, 0.f);
        } else if (actOut == 2) {
            v.x = v.x > 0.f ? v.x : expm1f(v.x);
            v.y = v.y > 0.f ? v.y : expm1f(v.y);
            v.z = v.z > 0.f ? v.z : expm1f(v.z);
            v.w = v.w > 0.f ? v.w : expm1f(v.w);
        }
        *(float4*)(C + (size_t)r * Nc + c0) = v;
    }
}

extern "C" void kernel_launch(void* const* d_in, const int* in_sizes, int n_in,
                              void* d_out, int out_size, void* d_ws, size_t ws_size,
                              hipStream_t stream) {
    const float* feat[2] = {(const float*)d_in[0], (const float*)d_in[1]};
    const int*   ei[2]   = {(const int*)d_in[2], (const int*)d_in[3]};
    const float* W1   = (const float*)d_in[4];
    const float* b1   = (const float*)d_in[5];
    const float* W2   = (const float*)d_in[6];
    const float* b2   = (const float*)d_in[7];
    const float* fc1W = (const float*)d_in[8];
    const float* fc1b = (const float*)d_in[9];
    const float* fc2W = (const float*)d_in[10];
    const float* fc2b = (const float*)d_in[11];
    int N = in_sizes[0] / NDIM;
    float* out = (float*)d_out;

    float* ws       = (float*)d_ws;
    float* norm_src = ws;                       // N
    float* norm_dst = ws + N;                   // N
    float* bufA     = ws + 2 * (size_t)N;       // N*128
    float* bufB     = bufA + (size_t)N * NDIM;  // N*256

    for (int g = 0; g < 2; ++g) {
        int E = in_sizes[2 + g] / 2;
        const int* src = ei[g];
        const int* dst = ei[g] + E;

        hipMemsetAsync(norm_src, 0, 2 * (size_t)N * sizeof(float), stream);
        deg_kernel<<<(E + 255) / 256, 256, 0, stream>>>(src, dst, norm_src, norm_dst, E);
        rsqrt_kernel<<<(2 * N + 255) / 256, 256, 0, stream>>>(norm_src, 2 * N);

        // L1: agg1 = scatter(feat * norm_src) -> bufA
        hipMemsetAsync(bufA, 0, (size_t)N * NDIM * sizeof(float), stream);
        scatter_kernel<<<(int)(((size_t)E * 32 + 255) / 256), 256, 0, stream>>>(
            feat[g], src, dst, norm_src, bufA, E);

        // X1 = relu(agg1 @ W1 * norm_dst + b1) -> bufB [N x 256]
        dim3 g1((N + 63) / 64, H2 / 64);
        gemm_kernel<<<g1, 256, 0, stream>>>(bufA, W1, bufB, N, NDIM, H2,
                                            nullptr, nullptr, 0, norm_dst, b1, 1);

        // T = X1 @ W2 -> bufA [N x 128]  (matmul-before-aggregate, linearity)
        dim3 g2((N + 63) / 64, NDIM / 64);
        gemm_kernel<<<g2, 256, 0, stream>>>(bufB, W2, bufA, N, H2, NDIM,
                                            nullptr, nullptr, 0, nullptr, nullptr, 0);

        // agg2 = scatter(T * norm_src) -> bufC (reuse bufB low half)
        float* bufC = bufB;
        hipMemsetAsync(bufC, 0, (size_t)N * NDIM * sizeof(float), stream);
        scatter_kernel<<<(int)(((size_t)E * 32 + 255) / 256), 256, 0, stream>>>(
            bufA, src, dst, norm_src, bufC, E);

        // Z = elu( relu(agg2 * norm_dst + b2) @ fc1W + fc1b ) -> bufA
        gemm_kernel<<<g2, 256, 0, stream>>>(bufC, fc1W, bufA, N, NDIM, NDIM,
                                            norm_dst, b2, 1, nullptr, fc1b, 2);

        // out = Z @ fc2W + fc2b -> d_out slice
        gemm_kernel<<<g2, 256, 0, stream>>>(bufA, fc2W, out + (size_t)g * N * NDIM, N, NDIM, NDIM,
                                            nullptr, nullptr, 0, nullptr, fc2b, 0);
    }
}

// Round 2
// 1234.263 us; speedup vs baseline: 4.9710x; 4.9710x over previous
//
#include <hip/hip_runtime.h>
#include <math.h>

#define NDIM 128   // in_dim = hid = out_dim
#define H2   256   // 2*hid

// ================= CSR build =================
__global__ void hist_kernel(const int* __restrict__ src, const int* __restrict__ dst,
                            int* __restrict__ cnt_out, int* __restrict__ cnt_in, int E) {
    int e = blockIdx.x * blockDim.x + threadIdx.x;
    if (e < E) {
        atomicAdd(&cnt_out[src[e]], 1);
        atomicAdd(&cnt_in[dst[e]], 1);
    }
}

__global__ void norm_kernel(const int* __restrict__ cnt_out, const int* __restrict__ cnt_in,
                            float* __restrict__ ns, float* __restrict__ nd, int n) {
    int i = blockIdx.x * blockDim.x + threadIdx.x;
    if (i < n) {
        int co = cnt_out[i], ci = cnt_in[i];
        ns[i] = rsqrtf((float)(co > 1 ? co : 1));
        nd[i] = rsqrtf((float)(ci > 1 ? ci : 1));
    }
}

// exclusive scan of cnt -> excl, per-block totals -> partials
__global__ void scan_block_kernel(const int* __restrict__ cnt, int* __restrict__ excl,
                                  int* __restrict__ partials, int n) {
    __shared__ int s[256];
    int i = blockIdx.x * 256 + threadIdx.x;
    int v = (i < n) ? cnt[i] : 0;
    s[threadIdx.x] = v;
    __syncthreads();
    for (int off = 1; off < 256; off <<= 1) {
        int t = (threadIdx.x >= off) ? s[threadIdx.x - off] : 0;
        __syncthreads();
        s[threadIdx.x] += t;
        __syncthreads();
    }
    if (i < n) excl[i] = s[threadIdx.x] - v;
    if (threadIdx.x == 255) partials[blockIdx.x] = s[255];
}

__global__ void scan_partials_kernel(int* __restrict__ partials, int nb) {
    if (blockIdx.x == 0 && threadIdx.x == 0) {
        int run = 0;
        for (int i = 0; i < nb; ++i) { int v = partials[i]; partials[i] = run; run += v; }
    }
}

__global__ void add_offsets_kernel(int* __restrict__ excl, const int* __restrict__ partials, int n) {
    int i = blockIdx.x * blockDim.x + threadIdx.x;
    if (i < n) excl[i] += partials[i >> 8];
}

__global__ void copy_int_kernel(const int* __restrict__ a, int* __restrict__ b, int n) {
    int i = blockIdx.x * blockDim.x + threadIdx.x;
    if (i < n) b[i] = a[i];
}

__global__ void fill_kernel(const int* __restrict__ src, const int* __restrict__ dst,
                            int* __restrict__ cursor, int* __restrict__ edge_src, int E) {
    int e = blockIdx.x * blockDim.x + threadIdx.x;
    if (e < E) {
        int pos = atomicAdd(&cursor[dst[e]], 1);
        edge_src[pos] = src[e];
    }
}

// ============ gather-aggregate: out[r] = sum_{j in CSR[r]} X[src_j] * rs[src_j] ============
// one 64-lane wave per row; lane holds float2 (128 floats/row). end pointer = cursor after fill.
__global__ __launch_bounds__(256) void gather_kernel(
    const float* __restrict__ X, const int* __restrict__ row_ptr,
    const int* __restrict__ row_end, const int* __restrict__ edge_src,
    const float* __restrict__ rs, float* __restrict__ out, int n) {
    int wave = threadIdx.x >> 6;
    int lane = threadIdx.x & 63;
    int r = blockIdx.x * 4 + wave;
    if (r >= n) return;
    int j = row_ptr[r];
    int end = row_end[r];
    float2 acc = make_float2(0.f, 0.f);
    for (; j + 1 < end; j += 2) {
        int s0 = edge_src[j], s1 = edge_src[j + 1];
        float sc0 = rs[s0], sc1 = rs[s1];
        float2 v0 = *(const float2*)(X + (size_t)s0 * NDIM + lane * 2);
        float2 v1 = *(const float2*)(X + (size_t)s1 * NDIM + lane * 2);
        acc.x += v0.x * sc0; acc.y += v0.y * sc0;
        acc.x += v1.x * sc1; acc.y += v1.y * sc1;
    }
    if (j < end) {
        int s0 = edge_src[j];
        float sc0 = rs[s0];
        float2 v0 = *(const float2*)(X + (size_t)s0 * NDIM + lane * 2);
        acc.x += v0.x * sc0; acc.y += v0.y * sc0;
    }
    *(float2*)(out + (size_t)r * NDIM + lane * 2) = acc;
}

// ================= fallback atomic scatter (ws too small) =================
__global__ void deg_kernel(const int* __restrict__ src, const int* __restrict__ dst,
                           float* __restrict__ deg_out, float* __restrict__ deg_in, int E) {
    int e = blockIdx.x * blockDim.x + threadIdx.x;
    if (e < E) {
        atomicAdd(&deg_out[src[e]], 1.0f);
        atomicAdd(&deg_in[dst[e]], 1.0f);
    }
}

__global__ void rsqrt_kernel(float* __restrict__ d, int n) {
    int i = blockIdx.x * blockDim.x + threadIdx.x;
    if (i < n) {
        float v = d[i];
        d[i] = rsqrtf(v > 1.0f ? v : 1.0f);
    }
}

__global__ void scatter_kernel(const float* __restrict__ X, const int* __restrict__ src,
                               const int* __restrict__ dst, const float* __restrict__ rs,
                               float* __restrict__ agg, int E) {
    int tid = blockIdx.x * blockDim.x + threadIdx.x;
    int e    = tid >> 5;
    int lane = tid & 31;
    if (e >= E) return;
    int s = src[e], d = dst[e];
    float sc = rs[s];
    const float4* xr = (const float4*)(X + (size_t)s * NDIM);
    float4 v = xr[lane];
    float* ar = agg + (size_t)d * NDIM + lane * 4;
    atomicAdd(ar + 0, v.x * sc);
    atomicAdd(ar + 1, v.y * sc);
    atomicAdd(ar + 2, v.z * sc);
    atomicAdd(ar + 3, v.w * sc);
}

// ================= fused GEMM =================
// C[M x Nc] = actOut( (actIn(A*rsIn[r]+bIn[k]) @ W) * rsOut[r] + bOut[c] )
__global__ __launch_bounds__(256) void gemm_kernel(
    const float* __restrict__ A, const float* __restrict__ W, float* __restrict__ C,
    int M, int K, int Nc,
    const float* __restrict__ rsIn, const float* __restrict__ bIn, int actIn,
    const float* __restrict__ rsOut, const float* __restrict__ bOut, int actOut)
{
    __shared__ float As[16][65];
    __shared__ float Bs[16][65];
    int tid = threadIdx.x;
    int tx = tid & 15, ty = tid >> 4;
    int rowBase = blockIdx.x * 64;
    int colBase = blockIdx.y * 64;

    int arow = tid >> 2;
    int akq  = (tid & 3) * 4;
    int grow = rowBase + arow;
    float rsv = 1.0f;
    if (rsIn && grow < M) rsv = rsIn[grow];
    int bk = tid >> 4;
    int bc = (tid & 15) * 4;

    float acc[4][4] = {};

    for (int k0 = 0; k0 < K; k0 += 16) {
        float4 av = make_float4(0.f, 0.f, 0.f, 0.f);
        if (grow < M) av = *(const float4*)(A + (size_t)grow * K + k0 + akq);
        if (rsIn) { av.x *= rsv; av.y *= rsv; av.z *= rsv; av.w *= rsv; }
        if (bIn) {
            av.x += bIn[k0 + akq + 0];
            av.y += bIn[k0 + akq + 1];
            av.z += bIn[k0 + akq + 2];
            av.w += bIn[k0 + akq + 3];
        }
        if (actIn == 1) {
            av.x = fmaxf(av.x, 0.f); av.y = fmaxf(av.y, 0.f);
            av.z = fmaxf(av.z, 0.f); av.w = fmaxf(av.w, 0.f);
        }
        As[akq + 0][arow] = av.x;
        As[akq + 1][arow] = av.y;
        As[akq + 2][arow] = av.z;
        As[akq + 3][arow] = av.w;

        float4 bv = *(const float4*)(W + (size_t)(k0 + bk) * Nc + colBase + bc);
        Bs[bk][bc + 0] = bv.x;
        Bs[bk][bc + 1] = bv.y;
        Bs[bk][bc + 2] = bv.z;
        Bs[bk][bc + 3] = bv.w;

        __syncthreads();
#pragma unroll
        for (int kk = 0; kk < 16; ++kk) {
            float a0 = As[kk][ty * 4 + 0];
            float a1 = As[kk][ty * 4 + 1];
            float a2 = As[kk][ty * 4 + 2];
            float a3 = As[kk][ty * 4 + 3];
            float b0 = Bs[kk][tx * 4 + 0];
            float b1 = Bs[kk][tx * 4 + 1];
            float b2 = Bs[kk][tx * 4 + 2];
            float b3 = Bs[kk][tx * 4 + 3];
            acc[0][0] += a0 * b0; acc[0][1] += a0 * b1; acc[0][2] += a0 * b2; acc[0][3] += a0 * b3;
            acc[1][0] += a1 * b0; acc[1][1] += a1 * b1; acc[1][2] += a1 * b2; acc[1][3] += a1 * b3;
            acc[2][0] += a2 * b0; acc[2][1] += a2 * b1; acc[2][2] += a2 * b2; acc[2][3] += a2 * b3;
            acc[3][0] += a3 * b0; acc[3][1] += a3 * b1; acc[3][2] += a3 * b2; acc[3][3] += a3 * b3;
        }
        __syncthreads();
    }

    int r0 = rowBase + ty * 4;
    int c0 = colBase + tx * 4;
#pragma unroll
    for (int i = 0; i < 4; ++i) {
        int r = r0 + i;
        if (r >= M) continue;
        float rs = rsOut ? rsOut[r] : 1.0f;
        float4 v;
        v.x = acc[i][0] * rs; v.y = acc[i][1] * rs; v.z = acc[i][2] * rs; v.w = acc[i][3] * rs;
        if (bOut) {
            v.x += bOut[c0 + 0]; v.y += bOut[c0 + 1]; v.z += bOut[c0 + 2]; v.w += bOut[c0 + 3];
        }
        if (actOut == 1) {
            v.x = fmaxf(v.x, 0.f); v.y = fmaxf(v.y, 0.f);
            v.z = fmaxf(v.z, 0.f); v.w = fmaxf(v.w, 0.f);
        } else if (actOut == 2) {
            v.x = v.x > 0.f ? v.x : expm1f(v.x);
            v.y = v.y > 0.f ? v.y : expm1f(v.y);
            v.z = v.z > 0.f ? v.z : expm1f(v.z);
            v.w = v.w > 0.f ? v.w : expm1f(v.w);
        }
        *(float4*)(C + (size_t)r * Nc + c0) = v;
    }
}

extern "C" void kernel_launch(void* const* d_in, const int* in_sizes, int n_in,
                              void* d_out, int out_size, void* d_ws, size_t ws_size,
                              hipStream_t stream) {
    const float* feat[2] = {(const float*)d_in[0], (const float*)d_in[1]};
    const int*   ei[2]   = {(const int*)d_in[2], (const int*)d_in[3]};
    const float* W1   = (const float*)d_in[4];
    const float* b1   = (const float*)d_in[5];
    const float* W2   = (const float*)d_in[6];
    const float* b2   = (const float*)d_in[7];
    const float* fc1W = (const float*)d_in[8];
    const float* fc1b = (const float*)d_in[9];
    const float* fc2W = (const float*)d_in[10];
    const float* fc2b = (const float*)d_in[11];
    int N = in_sizes[0] / NDIM;
    float* out = (float*)d_out;

    int Emax = 0;
    for (int g = 0; g < 2; ++g) { int E = in_sizes[2 + g] / 2; if (E > Emax) Emax = E; }
    int nb = (N + 255) / 256;

    // float region
    float* ws       = (float*)d_ws;
    float* norm_src = ws;                       // N
    float* norm_dst = ws + N;                   // N
    float* bufA     = ws + 2 * (size_t)N;       // N*128
    float* bufB     = bufA + (size_t)N * NDIM;  // N*256
    size_t float_words = 2 * (size_t)N + (size_t)N * NDIM + (size_t)N * H2;
    // int region (CSR):
    int* ibase    = (int*)(ws + float_words);
    int* row_ptr  = ibase;                 // N  (hist: cnt_out, then row_ptr)
    int* cursor   = ibase + N;             // N  (hist: cnt_in, then cursor/row_end)
    int* edge_src = ibase + 2 * (size_t)N; // Emax
    int* partials = edge_src + Emax;       // nb
    size_t need_bytes = float_words * sizeof(float) + (2 * (size_t)N + Emax + nb) * sizeof(int);
    bool use_csr = ws_size >= need_bytes;

    for (int g = 0; g < 2; ++g) {
        int E = in_sizes[2 + g] / 2;
        const int* src = ei[g];
        const int* dst = ei[g] + E;
        int egrid = (E + 255) / 256;
        int ngrid = (N + 255) / 256;

        if (use_csr) {
            // ---- build CSR by dst + norms ----
            hipMemsetAsync(ibase, 0, 2 * (size_t)N * sizeof(int), stream);
            hist_kernel<<<egrid, 256, 0, stream>>>(src, dst, row_ptr, cursor, E);  // cnt_out, cnt_in
            norm_kernel<<<ngrid, 256, 0, stream>>>(row_ptr, cursor, norm_src, norm_dst, N);
            // scan cnt_in (cursor) -> row_ptr (overwrites cnt_out: norms already extracted)
            scan_block_kernel<<<nb, 256, 0, stream>>>(cursor, row_ptr, partials, N);
            scan_partials_kernel<<<1, 64, 0, stream>>>(partials, nb);
            add_offsets_kernel<<<ngrid, 256, 0, stream>>>(row_ptr, partials, N);
            copy_int_kernel<<<ngrid, 256, 0, stream>>>(row_ptr, cursor, N);
            fill_kernel<<<egrid, 256, 0, stream>>>(src, dst, cursor, edge_src, E);
            // after fill: cursor[r] == row end

            int ggrid = (N + 3) / 4;
            // L1 aggregate: bufA = gather(feat * norm_src)
            gather_kernel<<<ggrid, 256, 0, stream>>>(feat[g], row_ptr, cursor, edge_src,
                                                     norm_src, bufA, N);
            dim3 g1((N + 63) / 64, H2 / 64);
            gemm_kernel<<<g1, 256, 0, stream>>>(bufA, W1, bufB, N, NDIM, H2,
                                                nullptr, nullptr, 0, norm_dst, b1, 1);
            dim3 g2((N + 63) / 64, NDIM / 64);
            gemm_kernel<<<g2, 256, 0, stream>>>(bufB, W2, bufA, N, H2, NDIM,
                                                nullptr, nullptr, 0, nullptr, nullptr, 0);
            // L2 aggregate: bufC = gather(bufA * norm_src)  (matmul-before-aggregate)
            float* bufC = bufB;
            gather_kernel<<<ggrid, 256, 0, stream>>>(bufA, row_ptr, cursor, edge_src,
                                                     norm_src, bufC, N);
            gemm_kernel<<<g2, 256, 0, stream>>>(bufC, fc1W, bufA, N, NDIM, NDIM,
                                                norm_dst, b2, 1, nullptr, fc1b, 2);
            gemm_kernel<<<g2, 256, 0, stream>>>(bufA, fc2W, out + (size_t)g * N * NDIM,
                                                N, NDIM, NDIM,
                                                nullptr, nullptr, 0, nullptr, fc2b, 0);
        } else {
            // ---- fallback: atomic scatter path ----
            hipMemsetAsync(norm_src, 0, 2 * (size_t)N * sizeof(float), stream);
            deg_kernel<<<egrid, 256, 0, stream>>>(src, dst, norm_src, norm_dst, E);
            rsqrt_kernel<<<(2 * N + 255) / 256, 256, 0, stream>>>(norm_src, 2 * N);
            hipMemsetAsync(bufA, 0, (size_t)N * NDIM * sizeof(float), stream);
            scatter_kernel<<<(int)(((size_t)E * 32 + 255) / 256), 256, 0, stream>>>(
                feat[g], src, dst, norm_src, bufA, E);
            dim3 g1((N + 63) / 64, H2 / 64);
            gemm_kernel<<<g1, 256, 0, stream>>>(bufA, W1, bufB, N, NDIM, H2,
                                                nullptr, nullptr, 0, norm_dst, b1, 1);
            dim3 g2((N + 63) / 64, NDIM / 64);
            gemm_kernel<<<g2, 256, 0, stream>>>(bufB, W2, bufA, N, H2, NDIM,
                                                nullptr, nullptr, 0, nullptr, nullptr, 0);
            float* bufC = bufB;
            hipMemsetAsync(bufC, 0, (size_t)N * NDIM * sizeof(float), stream);
            scatter_kernel<<<(int)(((size_t)E * 32 + 255) / 256), 256, 0, stream>>>(
                bufA, src, dst, norm_src, bufC, E);
            gemm_kernel<<<g2, 256, 0, stream>>>(bufC, fc1W, bufA, N, NDIM, NDIM,
                                                norm_dst, b2, 1, nullptr, fc1b, 2);
            gemm_kernel<<<g2, 256, 0, stream>>>(bufA, fc2W, out + (size_t)g * N * NDIM,
                                                N, NDIM, NDIM,
                                                nullptr, nullptr, 0, nullptr, fc2b, 0);
        }
    }
}

// Round 3
// 885.097 us; speedup vs baseline: 6.9320x; 1.3945x over previous
//
#include <hip/hip_runtime.h>
#include <math.h>

#define NDIM 128   // in_dim = hid = out_dim
#define H2   256   // 2*hid

typedef __attribute__((ext_vector_type(8))) short bf16x8;
typedef __attribute__((ext_vector_type(4))) float f32x4;

__device__ __forceinline__ unsigned short f2bf(float f) {
    unsigned int u = __float_as_uint(f);
    u += 0x7fffu + ((u >> 16) & 1u);           // RNE
    return (unsigned short)(u >> 16);
}
__device__ __forceinline__ float bf2f(unsigned short h) {
    return __uint_as_float(((unsigned int)h) << 16);
}
__device__ __forceinline__ void split2(float f, unsigned short& h, unsigned short& l) {
    h = f2bf(f);
    l = f2bf(f - bf2f(h));
}

// ================= CSR build =================
__global__ void hist_kernel(const int* __restrict__ src, const int* __restrict__ dst,
                            int* __restrict__ cnt_out, int* __restrict__ cnt_in, int E) {
    int e = blockIdx.x * blockDim.x + threadIdx.x;
    if (e < E) {
        atomicAdd(&cnt_out[src[e]], 1);
        atomicAdd(&cnt_in[dst[e]], 1);
    }
}

__global__ void norm_kernel(const int* __restrict__ cnt_out, const int* __restrict__ cnt_in,
                            float* __restrict__ ns, float* __restrict__ nd, int n) {
    int i = blockIdx.x * blockDim.x + threadIdx.x;
    if (i < n) {
        int co = cnt_out[i], ci = cnt_in[i];
        ns[i] = rsqrtf((float)(co > 1 ? co : 1));
        nd[i] = rsqrtf((float)(ci > 1 ? ci : 1));
    }
}

__global__ void scan_block_kernel(const int* __restrict__ cnt, int* __restrict__ excl,
                                  int* __restrict__ partials, int n) {
    __shared__ int s[256];
    int i = blockIdx.x * 256 + threadIdx.x;
    int v = (i < n) ? cnt[i] : 0;
    s[threadIdx.x] = v;
    __syncthreads();
    for (int off = 1; off < 256; off <<= 1) {
        int t = (threadIdx.x >= off) ? s[threadIdx.x - off] : 0;
        __syncthreads();
        s[threadIdx.x] += t;
        __syncthreads();
    }
    if (i < n) excl[i] = s[threadIdx.x] - v;
    if (threadIdx.x == 255) partials[blockIdx.x] = s[255];
}

__global__ void scan_partials_kernel(int* __restrict__ partials, int nb) {
    if (blockIdx.x == 0 && threadIdx.x == 0) {
        int run = 0;
        for (int i = 0; i < nb; ++i) { int v = partials[i]; partials[i] = run; run += v; }
    }
}

__global__ void add_offsets_kernel(int* __restrict__ excl, const int* __restrict__ partials, int n) {
    int i = blockIdx.x * blockDim.x + threadIdx.x;
    if (i < n) excl[i] += partials[i >> 8];
}

__global__ void copy_int_kernel(const int* __restrict__ a, int* __restrict__ b, int n) {
    int i = blockIdx.x * blockDim.x + threadIdx.x;
    if (i < n) b[i] = a[i];
}

__global__ void fill_kernel(const int* __restrict__ src, const int* __restrict__ dst,
                            int* __restrict__ cursor, int* __restrict__ edge_src, int E) {
    int e = blockIdx.x * blockDim.x + threadIdx.x;
    if (e < E) {
        int pos = atomicAdd(&cursor[dst[e]], 1);
        edge_src[pos] = src[e];
    }
}

// ================= weight prep: W [K][Nc] fp32 -> Wt hi/lo [Nc][K] bf16 =================
__global__ void wprep_kernel(const float* __restrict__ W, unsigned short* __restrict__ Wh,
                             unsigned short* __restrict__ Wl, int K, int Nc) {
    int i = blockIdx.x * blockDim.x + threadIdx.x;
    if (i >= K * Nc) return;
    int k = i / Nc, n = i % Nc;
    unsigned short h, l;
    split2(W[i], h, l);
    Wh[n * K + k] = h;
    Wl[n * K + k] = l;
}

// ===== gather-aggregate with split-bf16 output =====
// acc[r] = sum_{j in CSR[r]} X[src_j]*rs[src_j];
// if nd: v = acc*nd[r] + bias[col]; optional relu. Write hi/lo bf16.
__global__ __launch_bounds__(256) void gather_split_kernel(
    const float* __restrict__ X, const int* __restrict__ row_ptr,
    const int* __restrict__ row_end, const int* __restrict__ edge_src,
    const float* __restrict__ rs,
    unsigned short* __restrict__ outH, unsigned short* __restrict__ outL,
    const float* __restrict__ nd, const float* __restrict__ bias, int relu_on, int n)
{
    int wave = threadIdx.x >> 6;
    int lane = threadIdx.x & 63;
    int r = blockIdx.x * 4 + wave;
    if (r >= n) return;
    int j = row_ptr[r];
    int end = row_end[r];
    float2 acc = make_float2(0.f, 0.f);
    for (; j + 1 < end; j += 2) {
        int s0 = edge_src[j], s1 = edge_src[j + 1];
        float sc0 = rs[s0], sc1 = rs[s1];
        float2 v0 = *(const float2*)(X + (size_t)s0 * NDIM + lane * 2);
        float2 v1 = *(const float2*)(X + (size_t)s1 * NDIM + lane * 2);
        acc.x += v0.x * sc0; acc.y += v0.y * sc0;
        acc.x += v1.x * sc1; acc.y += v1.y * sc1;
    }
    if (j < end) {
        int s0 = edge_src[j];
        float sc0 = rs[s0];
        float2 v0 = *(const float2*)(X + (size_t)s0 * NDIM + lane * 2);
        acc.x += v0.x * sc0; acc.y += v0.y * sc0;
    }
    float a0 = acc.x, a1 = acc.y;
    if (nd) {
        float s = nd[r];
        a0 = a0 * s + bias[lane * 2 + 0];
        a1 = a1 * s + bias[lane * 2 + 1];
        if (relu_on) { a0 = fmaxf(a0, 0.f); a1 = fmaxf(a1, 0.f); }
    }
    unsigned short h0, l0, h1, l1;
    split2(a0, h0, l0); split2(a1, h1, l1);
    ushort2 vh; vh.x = h0; vh.y = h1;
    ushort2 vl; vl.x = l0; vl.y = l1;
    *(ushort2*)(outH + (size_t)r * NDIM + lane * 2) = vh;
    *(ushort2*)(outL + (size_t)r * NDIM + lane * 2) = vl;
}

// ================= split-bf16 MFMA GEMM =================
// A: hi/lo [M][K] bf16, B: hi/lo [Nc][K] bf16 (pre-transposed weights)
// acc = A*B (error-compensated: AhBh + AlBh + AhBl)
// epilogue: v = acc*rsOut[row] (opt) + bOut[col] (opt); act 0/1(relu)/2(elu)
// output: if CH: split pairs; else fp32 C.
// Block 256 thr = 4 waves; tile 64(M) x 128(N); wave w -> cols w*32..+32; BK=32.
__global__ __launch_bounds__(256) void mfma_gemm_kernel(
    const unsigned short* __restrict__ Ah_g, const unsigned short* __restrict__ Al_g,
    const unsigned short* __restrict__ Bh_g, const unsigned short* __restrict__ Bl_g,
    float* __restrict__ C, unsigned short* __restrict__ CH, unsigned short* __restrict__ CL,
    int M, int K, int Nc,
    const float* __restrict__ rsOut, const float* __restrict__ bOut, int act)
{
    __shared__ __align__(16) unsigned short Ah[64 * 40];
    __shared__ __align__(16) unsigned short Al[64 * 40];
    __shared__ __align__(16) unsigned short Bh[128 * 40];
    __shared__ __align__(16) unsigned short Bl[128 * 40];

    int tid  = threadIdx.x;
    int wave = tid >> 6, lane = tid & 63;
    int quad = lane >> 4, l16 = lane & 15;
    int rowBase = blockIdx.x * 64;
    int colBase = blockIdx.y * 128;

    f32x4 acc[4][2] = {};

    int s_row   = tid >> 2;            // 0..63
    int s_chunk = (tid & 3) * 8;       // k-offset 0,8,16,24

    for (int k0 = 0; k0 < K; k0 += 32) {
        // ---- stage A (64 x 32, hi+lo) ----
        int gr = rowBase + s_row;
        uint4 va_h = make_uint4(0, 0, 0, 0), va_l = make_uint4(0, 0, 0, 0);
        if (gr < M) {
            va_h = *(const uint4*)(Ah_g + (size_t)gr * K + k0 + s_chunk);
            va_l = *(const uint4*)(Al_g + (size_t)gr * K + k0 + s_chunk);
        }
        *(uint4*)(Ah + s_row * 40 + s_chunk) = va_h;
        *(uint4*)(Al + s_row * 40 + s_chunk) = va_l;
        // ---- stage B (128 x 32, hi+lo) ----
#pragma unroll
        for (int c = tid; c < 512; c += 256) {
            int bn = c >> 2, bc = (c & 3) * 8;
            uint4 vb_h = *(const uint4*)(Bh_g + (size_t)(colBase + bn) * K + k0 + bc);
            uint4 vb_l = *(const uint4*)(Bl_g + (size_t)(colBase + bn) * K + k0 + bc);
            *(uint4*)(Bh + bn * 40 + bc) = vb_h;
            *(uint4*)(Bl + bn * 40 + bc) = vb_l;
        }
        __syncthreads();

        bf16x8 af[4], alf[4], bhf[2], blf[2];
#pragma unroll
        for (int i = 0; i < 4; ++i) {
            af[i]  = *(const bf16x8*)(Ah + (i * 16 + l16) * 40 + quad * 8);
            alf[i] = *(const bf16x8*)(Al + (i * 16 + l16) * 40 + quad * 8);
        }
#pragma unroll
        for (int j = 0; j < 2; ++j) {
            bhf[j] = *(const bf16x8*)(Bh + (wave * 32 + j * 16 + l16) * 40 + quad * 8);
            blf[j] = *(const bf16x8*)(Bl + (wave * 32 + j * 16 + l16) * 40 + quad * 8);
        }
#pragma unroll
        for (int i = 0; i < 4; ++i)
#pragma unroll
            for (int j = 0; j < 2; ++j) {
                acc[i][j] = __builtin_amdgcn_mfma_f32_16x16x32_bf16(af[i],  bhf[j], acc[i][j], 0, 0, 0);
                acc[i][j] = __builtin_amdgcn_mfma_f32_16x16x32_bf16(alf[i], bhf[j], acc[i][j], 0, 0, 0);
                acc[i][j] = __builtin_amdgcn_mfma_f32_16x16x32_bf16(af[i],  blf[j], acc[i][j], 0, 0, 0);
            }
        __syncthreads();
    }

    // ---- epilogue: C/D layout col=lane&15, row=quad*4+reg ----
#pragma unroll
    for (int i = 0; i < 4; ++i) {
#pragma unroll
        for (int r = 0; r < 4; ++r) {
            int row = rowBase + i * 16 + quad * 4 + r;
            if (row >= M) continue;
            float rs = rsOut ? rsOut[row] : 1.0f;
#pragma unroll
            for (int j = 0; j < 2; ++j) {
                int col = colBase + wave * 32 + j * 16 + l16;
                float v = acc[i][j][r] * rs;
                if (bOut) v += bOut[col];
                if (act == 1) v = fmaxf(v, 0.f);
                else if (act == 2) v = v > 0.f ? v : expm1f(v);
                if (CH) {
                    unsigned short h, l;
                    split2(v, h, l);
                    CH[(size_t)row * Nc + col] = h;
                    CL[(size_t)row * Nc + col] = l;
                } else {
                    C[(size_t)row * Nc + col] = v;
                }
            }
        }
    }
}

extern "C" void kernel_launch(void* const* d_in, const int* in_sizes, int n_in,
                              void* d_out, int out_size, void* d_ws, size_t ws_size,
                              hipStream_t stream) {
    const float* feat[2] = {(const float*)d_in[0], (const float*)d_in[1]};
    const int*   ei[2]   = {(const int*)d_in[2], (const int*)d_in[3]};
    const float* W1   = (const float*)d_in[4];
    const float* b1   = (const float*)d_in[5];
    const float* W2   = (const float*)d_in[6];
    const float* b2   = (const float*)d_in[7];
    const float* fc1W = (const float*)d_in[8];
    const float* fc1b = (const float*)d_in[9];
    const float* fc2W = (const float*)d_in[10];
    const float* fc2b = (const float*)d_in[11];
    int N = in_sizes[0] / NDIM;
    float* out = (float*)d_out;

    int Emax = 0;
    for (int g = 0; g < 2; ++g) { int E = in_sizes[2 + g] / 2; if (E > Emax) Emax = E; }
    int nb = (N + 255) / 256;

    // ---- workspace layout ----
    char* p = (char*)d_ws;
    float* norm_src = (float*)p; p += (size_t)N * 4;
    float* norm_dst = (float*)p; p += (size_t)N * 4;
    // R1: 25.6MB region — A1 pairs / T fp32 / Z pairs (lifetimes disjoint)
    unsigned short* R1 = (unsigned short*)p; p += (size_t)N * NDIM * 2 * 2;
    // R2: 51.2MB region — X1 pairs / G pairs
    unsigned short* R2 = (unsigned short*)p; p += (size_t)N * H2 * 2 * 2;
    // weights (transposed + split)
    unsigned short* W1th = (unsigned short*)p; p += (size_t)NDIM * H2 * 2;
    unsigned short* W1tl = (unsigned short*)p; p += (size_t)NDIM * H2 * 2;
    unsigned short* W2th = (unsigned short*)p; p += (size_t)H2 * NDIM * 2;
    unsigned short* W2tl = (unsigned short*)p; p += (size_t)H2 * NDIM * 2;
    unsigned short* f1th = (unsigned short*)p; p += (size_t)NDIM * NDIM * 2;
    unsigned short* f1tl = (unsigned short*)p; p += (size_t)NDIM * NDIM * 2;
    unsigned short* f2th = (unsigned short*)p; p += (size_t)NDIM * NDIM * 2;
    unsigned short* f2tl = (unsigned short*)p; p += (size_t)NDIM * NDIM * 2;
    // CSR ints
    int* ibase    = (int*)p;
    int* row_ptr  = ibase;
    int* cursor   = ibase + N;
    int* edge_src = ibase + 2 * (size_t)N;
    int* partials = edge_src + Emax;

    unsigned short* A1h = R1;
    unsigned short* A1l = R1 + (size_t)N * NDIM;
    float*          T   = (float*)R1;
    unsigned short* Zh  = R1;
    unsigned short* Zl  = R1 + (size_t)N * NDIM;
    unsigned short* X1h = R2;
    unsigned short* X1l = R2 + (size_t)N * H2;
    unsigned short* Gh  = R2;
    unsigned short* Gl  = R2 + (size_t)N * NDIM;

    // ---- weight prep (once per launch) ----
    wprep_kernel<<<(NDIM * H2 + 255) / 256, 256, 0, stream>>>(W1, W1th, W1tl, NDIM, H2);
    wprep_kernel<<<(H2 * NDIM + 255) / 256, 256, 0, stream>>>(W2, W2th, W2tl, H2, NDIM);
    wprep_kernel<<<(NDIM * NDIM + 255) / 256, 256, 0, stream>>>(fc1W, f1th, f1tl, NDIM, NDIM);
    wprep_kernel<<<(NDIM * NDIM + 255) / 256, 256, 0, stream>>>(fc2W, f2th, f2tl, NDIM, NDIM);

    int mgrid = (N + 63) / 64;

    for (int g = 0; g < 2; ++g) {
        int E = in_sizes[2 + g] / 2;
        const int* src = ei[g];
        const int* dst = ei[g] + E;
        int egrid = (E + 255) / 256;
        int ngrid = (N + 255) / 256;
        int ggrid = (N + 3) / 4;

        // ---- CSR by dst + norms ----
        hipMemsetAsync(ibase, 0, 2 * (size_t)N * sizeof(int), stream);
        hist_kernel<<<egrid, 256, 0, stream>>>(src, dst, row_ptr, cursor, E);
        norm_kernel<<<ngrid, 256, 0, stream>>>(row_ptr, cursor, norm_src, norm_dst, N);
        scan_block_kernel<<<nb, 256, 0, stream>>>(cursor, row_ptr, partials, N);
        scan_partials_kernel<<<1, 64, 0, stream>>>(partials, nb);
        add_offsets_kernel<<<ngrid, 256, 0, stream>>>(row_ptr, partials, N);
        copy_int_kernel<<<ngrid, 256, 0, stream>>>(row_ptr, cursor, N);
        fill_kernel<<<egrid, 256, 0, stream>>>(src, dst, cursor, edge_src, E);

        // ---- agg1 = gather(feat * ns) -> A1 (split) ----
        gather_split_kernel<<<ggrid, 256, 0, stream>>>(
            feat[g], row_ptr, cursor, edge_src, norm_src, A1h, A1l,
            nullptr, nullptr, 0, N);

        // ---- X1 = relu(A1 @ W1 * nd + b1) -> split [N x 256] ----
        dim3 g1(mgrid, H2 / 128);
        mfma_gemm_kernel<<<g1, 256, 0, stream>>>(
            A1h, A1l, W1th, W1tl, nullptr, X1h, X1l,
            N, NDIM, H2, norm_dst, b1, 1);

        // ---- T = X1 @ W2 -> fp32 [N x 128] (linearity: matmul before aggregate) ----
        dim3 g2(mgrid, 1);
        mfma_gemm_kernel<<<g2, 256, 0, stream>>>(
            X1h, X1l, W2th, W2tl, T, nullptr, nullptr,
            N, H2, NDIM, nullptr, nullptr, 0);

        // ---- G = relu(gather(T * ns) * nd + b2) -> split [N x 128] ----
        gather_split_kernel<<<ggrid, 256, 0, stream>>>(
            T, row_ptr, cursor, edge_src, norm_src, Gh, Gl,
            norm_dst, b2, 1, N);

        // ---- Z = elu(G @ fc1W + fc1b) -> split [N x 128] ----
        mfma_gemm_kernel<<<g2, 256, 0, stream>>>(
            Gh, Gl, f1th, f1tl, nullptr, Zh, Zl,
            N, NDIM, NDIM, nullptr, fc1b, 2);

        // ---- out = Z @ fc2W + fc2b -> fp32 ----
        mfma_gemm_kernel<<<g2, 256, 0, stream>>>(
            Zh, Zl, f2th, f2tl, out + (size_t)g * N * NDIM, nullptr, nullptr,
            N, NDIM, NDIM, nullptr, fc2b, 0);
    }
}

// Round 4
// 775.004 us; speedup vs baseline: 7.9167x; 1.1421x over previous
//
#include <hip/hip_runtime.h>
#include <math.h>

#define NDIM 128   // in_dim = hid = out_dim
#define H2   256   // 2*hid
#define MAXG 2

typedef __attribute__((ext_vector_type(8))) short bf16x8;
typedef __attribute__((ext_vector_type(4))) float f32x4;

__device__ __forceinline__ unsigned short f2bf(float f) {
    unsigned int u = __float_as_uint(f);
    u += 0x7fffu + ((u >> 16) & 1u);           // RNE
    return (unsigned short)(u >> 16);
}
__device__ __forceinline__ float bf2f(unsigned short h) {
    return __uint_as_float(((unsigned int)h) << 16);
}
__device__ __forceinline__ void split2(float f, unsigned short& h, unsigned short& l) {
    h = f2bf(f);
    l = f2bf(f - bf2f(h));
}

// ================= CSR build (batched over graphs via blockIdx.y) =================
struct CsrArgs {
    const int* src[MAXG]; const int* dst[MAXG];
    int* cnt_out[MAXG];   // also row_ptr after scan
    int* cnt_in[MAXG];    // also cursor / row_end
    int* edge_src[MAXG]; int* partials[MAXG];
    float* ns[MAXG]; float* nd[MAXG];
    int E[MAXG]; int n; int nb;
};

__global__ void hist_b(CsrArgs a) {
    int g = blockIdx.y;
    int e = blockIdx.x * 256 + threadIdx.x;
    if (e < a.E[g]) {
        atomicAdd(&a.cnt_out[g][a.src[g][e]], 1);
        atomicAdd(&a.cnt_in[g][a.dst[g][e]], 1);
    }
}

__global__ void norm_b(CsrArgs a) {
    int g = blockIdx.y;
    int i = blockIdx.x * 256 + threadIdx.x;
    if (i < a.n) {
        int co = a.cnt_out[g][i], ci = a.cnt_in[g][i];
        a.ns[g][i] = rsqrtf((float)(co > 1 ? co : 1));
        a.nd[g][i] = rsqrtf((float)(ci > 1 ? ci : 1));
    }
}

// scan cnt_in -> cnt_out (block-local exclusive), block totals -> partials
__global__ void scan_block_b(CsrArgs a) {
    int g = blockIdx.y;
    __shared__ int s[256];
    int i = blockIdx.x * 256 + threadIdx.x;
    int v = (i < a.n) ? a.cnt_in[g][i] : 0;
    s[threadIdx.x] = v;
    __syncthreads();
    for (int off = 1; off < 256; off <<= 1) {
        int t = (threadIdx.x >= off) ? s[threadIdx.x - off] : 0;
        __syncthreads();
        s[threadIdx.x] += t;
        __syncthreads();
    }
    if (i < a.n) a.cnt_out[g][i] = s[threadIdx.x] - v;
    if (threadIdx.x == 255) a.partials[g][blockIdx.x] = s[255];
}

// exclusive scan of partials (nb <= 256 fast path)
__global__ void scan_partials_b(CsrArgs a) {
    int g = blockIdx.y;
    if (a.nb <= 256) {
        __shared__ int s[256];
        int t = threadIdx.x;
        int v = (t < a.nb) ? a.partials[g][t] : 0;
        s[t] = v;
        __syncthreads();
        for (int off = 1; off < 256; off <<= 1) {
            int u = (t >= off) ? s[t - off] : 0;
            __syncthreads();
            s[t] += u;
            __syncthreads();
        }
        if (t < a.nb) a.partials[g][t] = s[t] - v;
    } else if (threadIdx.x == 0) {
        int run = 0;
        for (int i = 0; i < a.nb; ++i) { int v = a.partials[g][i]; a.partials[g][i] = run; run += v; }
    }
}

// row_ptr += partials; cursor = row_ptr  (fused copy)
__global__ void add_offsets_b(CsrArgs a) {
    int g = blockIdx.y;
    int i = blockIdx.x * 256 + threadIdx.x;
    if (i < a.n) {
        int v = a.cnt_out[g][i] + a.partials[g][i >> 8];
        a.cnt_out[g][i] = v;
        a.cnt_in[g][i] = v;
    }
}

__global__ void fill_b(CsrArgs a) {
    int g = blockIdx.y;
    int e = blockIdx.x * 256 + threadIdx.x;
    if (e < a.E[g]) {
        int pos = atomicAdd(&a.cnt_in[g][a.dst[g][e]], 1);
        a.edge_src[g][pos] = a.src[g][e];
    }
}

// ================= weight prep: all 4 weights, transposed + split =================
__global__ void wprep_all(const float* __restrict__ W1, const float* __restrict__ W2,
                          const float* __restrict__ F1, const float* __restrict__ F2,
                          unsigned short* __restrict__ W1h, unsigned short* __restrict__ W1l,
                          unsigned short* __restrict__ W2h, unsigned short* __restrict__ W2l,
                          unsigned short* __restrict__ F1h, unsigned short* __restrict__ F1l,
                          unsigned short* __restrict__ F2h, unsigned short* __restrict__ F2l) {
    int i = blockIdx.x * 256 + threadIdx.x;
    const float* Wsrc; unsigned short *Hd, *Ld; int K, Nc, idx;
    if (i < 32768)       { Wsrc = W1; Hd = W1h; Ld = W1l; K = 128; Nc = 256; idx = i; }
    else if (i < 65536)  { Wsrc = W2; Hd = W2h; Ld = W2l; K = 256; Nc = 128; idx = i - 32768; }
    else if (i < 81920)  { Wsrc = F1; Hd = F1h; Ld = F1l; K = 128; Nc = 128; idx = i - 65536; }
    else                 { Wsrc = F2; Hd = F2h; Ld = F2l; K = 128; Nc = 128; idx = i - 81920; }
    int k = idx / Nc, n = idx % Nc;
    unsigned short h, l;
    split2(Wsrc[idx], h, l);
    Hd[n * K + k] = h;
    Ld[n * K + k] = l;
}

// ===== gather-aggregate (batched), half-wave per row, float4/lane, 4-deep unroll =====
struct GatherArgs {
    const float* X[MAXG];
    const int* row_ptr[MAXG]; const int* row_end[MAXG]; const int* edge_src[MAXG];
    const float* ns[MAXG]; const float* nd[MAXG];
    unsigned short* outH[MAXG]; unsigned short* outL[MAXG];
    const float* bias; int use_nd; int relu_on; int n;
};

__global__ __launch_bounds__(256) void gather_split_b(GatherArgs a) {
    int g = blockIdx.y;
    int half = threadIdx.x >> 5;
    int lane = threadIdx.x & 31;
    int r = blockIdx.x * 8 + half;
    if (r >= a.n) return;
    int j = a.row_ptr[g][r];
    int end = a.row_end[g][r];
    const int* ep = a.edge_src[g];
    const float* X = a.X[g];
    const float* rs = a.ns[g];
    int base = lane * 4;
    float4 acc = make_float4(0.f, 0.f, 0.f, 0.f);
    for (; j + 3 < end; j += 4) {
        int s0 = ep[j], s1 = ep[j + 1], s2 = ep[j + 2], s3 = ep[j + 3];
        float c0 = rs[s0], c1 = rs[s1], c2 = rs[s2], c3 = rs[s3];
        float4 v0 = *(const float4*)(X + (size_t)s0 * NDIM + base);
        float4 v1 = *(const float4*)(X + (size_t)s1 * NDIM + base);
        float4 v2 = *(const float4*)(X + (size_t)s2 * NDIM + base);
        float4 v3 = *(const float4*)(X + (size_t)s3 * NDIM + base);
        acc.x += v0.x * c0 + v1.x * c1 + v2.x * c2 + v3.x * c3;
        acc.y += v0.y * c0 + v1.y * c1 + v2.y * c2 + v3.y * c3;
        acc.z += v0.z * c0 + v1.z * c1 + v2.z * c2 + v3.z * c3;
        acc.w += v0.w * c0 + v1.w * c1 + v2.w * c2 + v3.w * c3;
    }
    for (; j < end; ++j) {
        int s0 = ep[j];
        float c0 = rs[s0];
        float4 v0 = *(const float4*)(X + (size_t)s0 * NDIM + base);
        acc.x += v0.x * c0; acc.y += v0.y * c0;
        acc.z += v0.z * c0; acc.w += v0.w * c0;
    }
    float v[4] = {acc.x, acc.y, acc.z, acc.w};
    if (a.use_nd) {
        float s = a.nd[g][r];
#pragma unroll
        for (int i = 0; i < 4; ++i) {
            v[i] = v[i] * s + a.bias[base + i];
            if (a.relu_on) v[i] = fmaxf(v[i], 0.f);
        }
    }
    unsigned short h[4], l[4];
#pragma unroll
    for (int i = 0; i < 4; ++i) split2(v[i], h[i], l[i]);
    *(ushort4*)(a.outH[g] + (size_t)r * NDIM + base) = make_ushort4(h[0], h[1], h[2], h[3]);
    *(ushort4*)(a.outL[g] + (size_t)r * NDIM + base) = make_ushort4(l[0], l[1], l[2], l[3]);
}

// ================= split-bf16 MFMA GEMM (batched via blockIdx.z) =================
struct GemmArgs {
    const unsigned short* Ah[MAXG]; const unsigned short* Al[MAXG];
    const unsigned short* Bh; const unsigned short* Bl;
    float* C[MAXG]; unsigned short* CH[MAXG]; unsigned short* CL[MAXG];
    const float* rsOut[MAXG]; const float* bOut;
    int M, K, Nc, act, has_rs, has_b, split_out;
};

__global__ __launch_bounds__(256) void mfma_gemm_b(GemmArgs a) {
    __shared__ __align__(16) unsigned short Ah[64 * 40];
    __shared__ __align__(16) unsigned short Al[64 * 40];
    __shared__ __align__(16) unsigned short Bh[128 * 40];
    __shared__ __align__(16) unsigned short Bl[128 * 40];

    int g = blockIdx.z;
    const unsigned short* Ah_g = a.Ah[g];
    const unsigned short* Al_g = a.Al[g];

    int tid  = threadIdx.x;
    int wave = tid >> 6, lane = tid & 63;
    int quad = lane >> 4, l16 = lane & 15;
    int rowBase = blockIdx.x * 64;
    int colBase = blockIdx.y * 128;
    int M = a.M, K = a.K, Nc = a.Nc;

    f32x4 acc[4][2] = {};

    int s_row   = tid >> 2;
    int s_chunk = (tid & 3) * 8;

    for (int k0 = 0; k0 < K; k0 += 32) {
        int gr = rowBase + s_row;
        uint4 va_h = make_uint4(0, 0, 0, 0), va_l = make_uint4(0, 0, 0, 0);
        if (gr < M) {
            va_h = *(const uint4*)(Ah_g + (size_t)gr * K + k0 + s_chunk);
            va_l = *(const uint4*)(Al_g + (size_t)gr * K + k0 + s_chunk);
        }
        *(uint4*)(Ah + s_row * 40 + s_chunk) = va_h;
        *(uint4*)(Al + s_row * 40 + s_chunk) = va_l;
#pragma unroll
        for (int c = tid; c < 512; c += 256) {
            int bn = c >> 2, bc = (c & 3) * 8;
            uint4 vb_h = *(const uint4*)(a.Bh + (size_t)(colBase + bn) * K + k0 + bc);
            uint4 vb_l = *(const uint4*)(a.Bl + (size_t)(colBase + bn) * K + k0 + bc);
            *(uint4*)(Bh + bn * 40 + bc) = vb_h;
            *(uint4*)(Bl + bn * 40 + bc) = vb_l;
        }
        __syncthreads();

        bf16x8 af[4], alf[4], bhf[2], blf[2];
#pragma unroll
        for (int i = 0; i < 4; ++i) {
            af[i]  = *(const bf16x8*)(Ah + (i * 16 + l16) * 40 + quad * 8);
            alf[i] = *(const bf16x8*)(Al + (i * 16 + l16) * 40 + quad * 8);
        }
#pragma unroll
        for (int j = 0; j < 2; ++j) {
            bhf[j] = *(const bf16x8*)(Bh + (wave * 32 + j * 16 + l16) * 40 + quad * 8);
            blf[j] = *(const bf16x8*)(Bl + (wave * 32 + j * 16 + l16) * 40 + quad * 8);
        }
#pragma unroll
        for (int i = 0; i < 4; ++i)
#pragma unroll
            for (int j = 0; j < 2; ++j) {
                acc[i][j] = __builtin_amdgcn_mfma_f32_16x16x32_bf16(af[i],  bhf[j], acc[i][j], 0, 0, 0);
                acc[i][j] = __builtin_amdgcn_mfma_f32_16x16x32_bf16(alf[i], bhf[j], acc[i][j], 0, 0, 0);
                acc[i][j] = __builtin_amdgcn_mfma_f32_16x16x32_bf16(af[i],  blf[j], acc[i][j], 0, 0, 0);
            }
        __syncthreads();
    }

    // epilogue: C/D layout col=lane&15, row=quad*4+reg
#pragma unroll
    for (int i = 0; i < 4; ++i) {
#pragma unroll
        for (int r = 0; r < 4; ++r) {
            int row = rowBase + i * 16 + quad * 4 + r;
            if (row >= M) continue;
            float rs = a.has_rs ? a.rsOut[g][row] : 1.0f;
#pragma unroll
            for (int j = 0; j < 2; ++j) {
                int col = colBase + wave * 32 + j * 16 + l16;
                float v = acc[i][j][r] * rs;
                if (a.has_b) v += a.bOut[col];
                if (a.act == 1) v = fmaxf(v, 0.f);
                else if (a.act == 2) v = v > 0.f ? v : expm1f(v);
                if (a.split_out) {
                    unsigned short h, l;
                    split2(v, h, l);
                    a.CH[g][(size_t)row * Nc + col] = h;
                    a.CL[g][(size_t)row * Nc + col] = l;
                } else {
                    a.C[g][(size_t)row * Nc + col] = v;
                }
            }
        }
    }
}

extern "C" void kernel_launch(void* const* d_in, const int* in_sizes, int n_in,
                              void* d_out, int out_size, void* d_ws, size_t ws_size,
                              hipStream_t stream) {
    const float* feat[2] = {(const float*)d_in[0], (const float*)d_in[1]};
    const int*   ei[2]   = {(const int*)d_in[2], (const int*)d_in[3]};
    const float* W1   = (const float*)d_in[4];
    const float* b1   = (const float*)d_in[5];
    const float* W2   = (const float*)d_in[6];
    const float* b2   = (const float*)d_in[7];
    const float* fc1W = (const float*)d_in[8];
    const float* fc1b = (const float*)d_in[9];
    const float* fc2W = (const float*)d_in[10];
    const float* fc2b = (const float*)d_in[11];
    int N = in_sizes[0] / NDIM;
    float* out = (float*)d_out;

    int Emax = 0;
    for (int g = 0; g < 2; ++g) { int E = in_sizes[2 + g] / 2; if (E > Emax) Emax = E; }
    int nb = (N + 255) / 256;

    // ---- choose resident graph count by workspace ----
    size_t per_graph = 2 * (size_t)N * 4                 // ns + nd
                     + (size_t)N * NDIM * 2 * 2          // R1 (A1/T/Z)
                     + (size_t)N * H2 * 2 * 2            // R2 (X1/G)
                     + 2 * (size_t)N * 4                 // cnt ints
                     + (size_t)Emax * 4                  // edge_src
                     + (size_t)nb * 4;                   // partials
    size_t w_bytes = (size_t)(32768 + 32768 + 16384 + 16384) * 2 * 2;
    int ng = (ws_size >= 2 * per_graph + w_bytes) ? 2 : 1;

    // ---- workspace layout for ng resident graphs ----
    char* p = (char*)d_ws;
    float* ns_[MAXG]; float* nd_[MAXG];
    for (int i = 0; i < ng; ++i) { ns_[i] = (float*)p; p += (size_t)N * 4; }
    for (int i = 0; i < ng; ++i) { nd_[i] = (float*)p; p += (size_t)N * 4; }
    unsigned short* R1[MAXG]; unsigned short* R2[MAXG];
    for (int i = 0; i < ng; ++i) { R1[i] = (unsigned short*)p; p += (size_t)N * NDIM * 2 * 2; }
    for (int i = 0; i < ng; ++i) { R2[i] = (unsigned short*)p; p += (size_t)N * H2 * 2 * 2; }
    unsigned short* W1th = (unsigned short*)p; p += (size_t)NDIM * H2 * 2;
    unsigned short* W1tl = (unsigned short*)p; p += (size_t)NDIM * H2 * 2;
    unsigned short* W2th = (unsigned short*)p; p += (size_t)H2 * NDIM * 2;
    unsigned short* W2tl = (unsigned short*)p; p += (size_t)H2 * NDIM * 2;
    unsigned short* f1th = (unsigned short*)p; p += (size_t)NDIM * NDIM * 2;
    unsigned short* f1tl = (unsigned short*)p; p += (size_t)NDIM * NDIM * 2;
    unsigned short* f2th = (unsigned short*)p; p += (size_t)NDIM * NDIM * 2;
    unsigned short* f2tl = (unsigned short*)p; p += (size_t)NDIM * NDIM * 2;
    int* cnt_base = (int*)p; p += (size_t)ng * 2 * N * 4;   // [row_ptr|cursor] per graph, contiguous
    int* esrc_[MAXG];
    for (int i = 0; i < ng; ++i) { esrc_[i] = (int*)p; p += (size_t)Emax * 4; }
    int* part_[MAXG];
    for (int i = 0; i < ng; ++i) { part_[i] = (int*)p; p += (size_t)nb * 4; }

    // ---- weight prep (once) ----
    wprep_all<<<384, 256, 0, stream>>>(W1, W2, fc1W, fc2W,
                                       W1th, W1tl, W2th, W2tl, f1th, f1tl, f2th, f2tl);

    int mgrid = (N + 63) / 64;
    int ngrid = (N + 255) / 256;
    int ggrid = (N + 7) / 8;
    int passes = 2 / ng;

    for (int pass = 0; pass < passes; ++pass) {
        int egrid = 0;
        CsrArgs ca = {};
        ca.n = N; ca.nb = nb;
        for (int i = 0; i < ng; ++i) {
            int gi = pass * ng + i;
            int E = in_sizes[2 + gi] / 2;
            ca.src[i] = ei[gi];
            ca.dst[i] = ei[gi] + E;
            ca.E[i] = E;
            ca.cnt_out[i]  = cnt_base + (size_t)i * 2 * N;
            ca.cnt_in[i]   = cnt_base + (size_t)i * 2 * N + N;
            ca.edge_src[i] = esrc_[i];
            ca.partials[i] = part_[i];
            ca.ns[i] = ns_[i]; ca.nd[i] = nd_[i];
            int eg = (E + 255) / 256;
            if (eg > egrid) egrid = eg;
        }
        hipMemsetAsync(cnt_base, 0, (size_t)ng * 2 * N * sizeof(int), stream);
        hist_b<<<dim3(egrid, ng), 256, 0, stream>>>(ca);
        norm_b<<<dim3(ngrid, ng), 256, 0, stream>>>(ca);
        scan_block_b<<<dim3(nb, ng), 256, 0, stream>>>(ca);
        scan_partials_b<<<dim3(1, ng), 256, 0, stream>>>(ca);
        add_offsets_b<<<dim3(ngrid, ng), 256, 0, stream>>>(ca);
        fill_b<<<dim3(egrid, ng), 256, 0, stream>>>(ca);

        // per-slot buffer aliases
        unsigned short *A1h[MAXG], *A1l[MAXG], *X1h[MAXG], *X1l[MAXG];
        unsigned short *Gh[MAXG], *Gl[MAXG], *Zh[MAXG], *Zl[MAXG];
        float* T[MAXG];
        for (int i = 0; i < ng; ++i) {
            A1h[i] = R1[i]; A1l[i] = R1[i] + (size_t)N * NDIM;
            T[i]   = (float*)R1[i];
            Zh[i]  = R1[i]; Zl[i]  = R1[i] + (size_t)N * NDIM;
            X1h[i] = R2[i]; X1l[i] = R2[i] + (size_t)N * H2;
            Gh[i]  = R2[i]; Gl[i]  = R2[i] + (size_t)N * NDIM;
        }

        // ---- gather1: A1 = split(gather(feat * ns)) ----
        GatherArgs ga = {};
        ga.n = N; ga.use_nd = 0; ga.relu_on = 0; ga.bias = nullptr;
        for (int i = 0; i < ng; ++i) {
            int gi = pass * ng + i;
            ga.X[i] = feat[gi];
            ga.row_ptr[i] = ca.cnt_out[i]; ga.row_end[i] = ca.cnt_in[i];
            ga.edge_src[i] = esrc_[i]; ga.ns[i] = ns_[i]; ga.nd[i] = nd_[i];
            ga.outH[i] = A1h[i]; ga.outL[i] = A1l[i];
        }
        gather_split_b<<<dim3(ggrid, ng), 256, 0, stream>>>(ga);

        // ---- gemm1: X1 = relu(A1 @ W1 * nd + b1), split out ----
        GemmArgs g1 = {};
        g1.Bh = W1th; g1.Bl = W1tl; g1.bOut = b1;
        g1.M = N; g1.K = NDIM; g1.Nc = H2; g1.act = 1; g1.has_rs = 1; g1.has_b = 1; g1.split_out = 1;
        for (int i = 0; i < ng; ++i) {
            g1.Ah[i] = A1h[i]; g1.Al[i] = A1l[i];
            g1.CH[i] = X1h[i]; g1.CL[i] = X1l[i]; g1.rsOut[i] = nd_[i];
        }
        mfma_gemm_b<<<dim3(mgrid, H2 / 128, ng), 256, 0, stream>>>(g1);

        // ---- gemm2: T = X1 @ W2, fp32 out ----
        GemmArgs g2 = {};
        g2.Bh = W2th; g2.Bl = W2tl;
        g2.M = N; g2.K = H2; g2.Nc = NDIM; g2.act = 0; g2.has_rs = 0; g2.has_b = 0; g2.split_out = 0;
        for (int i = 0; i < ng; ++i) {
            g2.Ah[i] = X1h[i]; g2.Al[i] = X1l[i];
            g2.C[i] = T[i];
        }
        mfma_gemm_b<<<dim3(mgrid, 1, ng), 256, 0, stream>>>(g2);

        // ---- gather2: G = split(relu(gather(T * ns) * nd + b2)) ----
        GatherArgs gb = ga;
        gb.use_nd = 1; gb.relu_on = 1; gb.bias = b2;
        for (int i = 0; i < ng; ++i) {
            gb.X[i] = T[i];
            gb.outH[i] = Gh[i]; gb.outL[i] = Gl[i];
        }
        gather_split_b<<<dim3(ggrid, ng), 256, 0, stream>>>(gb);

        // ---- gemm3: Z = elu(G @ fc1W + fc1b), split out ----
        GemmArgs g3 = {};
        g3.Bh = f1th; g3.Bl = f1tl; g3.bOut = fc1b;
        g3.M = N; g3.K = NDIM; g3.Nc = NDIM; g3.act = 2; g3.has_rs = 0; g3.has_b = 1; g3.split_out = 1;
        for (int i = 0; i < ng; ++i) {
            g3.Ah[i] = Gh[i]; g3.Al[i] = Gl[i];
            g3.CH[i] = Zh[i]; g3.CL[i] = Zl[i];
        }
        mfma_gemm_b<<<dim3(mgrid, 1, ng), 256, 0, stream>>>(g3);

        // ---- gemm4: out = Z @ fc2W + fc2b, fp32 out ----
        GemmArgs g4 = {};
        g4.Bh = f2th; g4.Bl = f2tl; g4.bOut = fc2b;
        g4.M = N; g4.K = NDIM; g4.Nc = NDIM; g4.act = 0; g4.has_rs = 0; g4.has_b = 1; g4.split_out = 0;
        for (int i = 0; i < ng; ++i) {
            int gi = pass * ng + i;
            g4.Ah[i] = Zh[i]; g4.Al[i] = Zl[i];
            g4.C[i] = out + (size_t)gi * N * NDIM;
        }
        mfma_gemm_b<<<dim3(mgrid, 1, ng), 256, 0, stream>>>(g4);
    }
}